// Round 12
// baseline (250.196 us; speedup 1.0000x reference)
//
#include <hip/hip_runtime.h>
#include <math.h>

// MMD loss, single-pass fp16 MFMA, FULLY FUSED persistent-block kernel.
// N=M=4096, D=1024, sigma^2=2025. x -> xh = fp16(x) (RNE); norms computed
// FROM THE ROUNDED vectors so the kernel evaluates the exact MMD of the
// perturbed sets {xh},{yh}. fp64 cross-block accumulation.
// R11 failed (absmax 9.3e-5): MISSING __syncthreads() between phase 1 and
// the release-add — t0 released while other waves' Xh/Yh stores were still
// in flight -> readers saw a few stale rows. Fixed here. Finalize ordering
// now uses __ATOMIC_RELEASE on the arrival counter (L2 *writeback* only —
// R4's poison was the per-block *invalidate*; writebacks don't evict
// others' clean cached tiles).
//   phase 1: each block converts 16 rows (fp32->fp16 + norms)
//   barrier: __syncthreads; release-add / relaxed-spin / ONE acquire-load
//   phase 2: exactly 4 tiles per block (2080 = 520*4; R5's proven K-loop)
//   finalize: fp64 atomicAdd(acc); release-add cnt1; last block writes out

typedef _Float16 f16_t;
typedef _Float16 f16x4 __attribute__((ext_vector_type(4)));
typedef _Float16 f16x8 __attribute__((ext_vector_type(8)));
typedef float floatx4 __attribute__((ext_vector_type(4)));

#define NROWS 4096
#define MROWS 4096
#define DDIM  1024
#define BM    128
#define BK    32                      // fp16 elements per K-step (64 B/row)
#define TILE  (BM * BK)               // 4096 f16 per tile (8 KB)
#define NT    (NROWS / BM)            // 32 tiles per dim
#define TRI   (NT * (NT + 1) / 2)     // 528 triangular tiles
#define NTILE (2 * TRI + NT * NT)     // 2080 tiles
#define PBLK  520                     // persistent blocks; 2080/520 = 4 exactly
#define TPB   (NTILE / PBLK)          // 4 tiles per block

__global__ __launch_bounds__(256, 4) void mmd_fused(
    const float* __restrict__ X, const float* __restrict__ Y,
    f16_t* __restrict__ Xh, f16_t* __restrict__ Yh,
    float* __restrict__ nx, float* __restrict__ ny,
    unsigned* __restrict__ cnt0, unsigned* __restrict__ cnt1,
    double* __restrict__ acc, float* __restrict__ out) {
    __shared__ __align__(16) f16_t lds[2 * TILE];
    __shared__ double wred[4];

    const int pb   = blockIdx.x;
    const int t    = threadIdx.x;
    const int wave = t >> 6;
    const int lane = t & 63;

    // ---------------- phase 1: convert 16 rows (4 rows per wave) ----------
    #pragma unroll
    for (int i = 0; i < 4; i++) {
        int row = pb * 16 + wave * 4 + i;         // 0..8319
        if (row < NROWS + MROWS) {
            const float* src;
            f16_t* dst;
            float* nrm;
            int r;
            if (row < NROWS) {
                r = row;         src = X + (size_t)r * DDIM;
                dst = Xh + (size_t)r * DDIM;  nrm = nx;
            } else {
                r = row - NROWS; src = Y + (size_t)r * DDIM;
                dst = Yh + (size_t)r * DDIM;  nrm = ny;
            }
            const float4* s4 = (const float4*)src;   // 256 float4 per row
            f16x4* d4 = (f16x4*)dst;
            float s = 0.f;
            #pragma unroll
            for (int c = 0; c < 4; c++) {
                float4 v = s4[c * 64 + lane];
                f16x4 h;
                h[0] = (f16_t)v.x; h[1] = (f16_t)v.y;
                h[2] = (f16_t)v.z; h[3] = (f16_t)v.w;
                d4[c * 64 + lane] = h;
                float h0 = (float)h[0], h1 = (float)h[1];
                float h2 = (float)h[2], h3 = (float)h[3];
                s += h0 * h0 + h1 * h1 + h2 * h2 + h3 * h3;
            }
            #pragma unroll
            for (int off = 32; off > 0; off >>= 1) s += __shfl_down(s, off);
            if (lane == 0) nrm[r] = s;
        }
    }

    // CRITICAL (R11 bug): all waves' stores must drain before t0 releases.
    // __syncthreads emits per-wave s_waitcnt vmcnt(0) before s_barrier.
    __syncthreads();

    // ---------------- device barrier (release / relaxed-spin / acquire) ---
    if (t == 0) {
        __hip_atomic_fetch_add(cnt0, 1u, __ATOMIC_RELEASE,
                               __HIP_MEMORY_SCOPE_AGENT);
        while (__hip_atomic_load(cnt0, __ATOMIC_RELAXED,
                                 __HIP_MEMORY_SCOPE_AGENT) < PBLK)
            __builtin_amdgcn_s_sleep(8);
        // single acquire: synchronizes with every release-add in the chain
        (void)__hip_atomic_load(cnt0, __ATOMIC_ACQUIRE,
                                __HIP_MEMORY_SCOPE_AGENT);
    }
    __syncthreads();

    // ---------------- phase 2: exactly 4 tiles per block ------------------
    const int wm = wave >> 1;
    const int wn = wave & 1;
    const int lrow = lane >> 2;          // staging: 0..15 within row-group
    const int lcol = (lane & 3) * 8;     // 16-B chunk
    const int m    = lane & 15;          // frag row in 16x16 subtile
    const int quad = lane >> 4;          // k-chunk: k = quad*8 + j

    double mysum = 0.0;

    for (int g = 0; g < TPB; g++) {
        const int b = pb * TPB + g;      // 0..2079, adjacent -> L2 reuse
        const f16_t *A, *B;
        const float *nA, *nB;
        int tr, tc;
        double coef;
        if (b < 2 * TRI) {
            int u = (b < TRI) ? b : b - TRI;
            int r = 0;
            while (u >= NT - r) { u -= NT - r; r++; }
            tr = r; tc = r + u;
            double w = (tr == tc) ? 1.0 : 2.0;   // off-diag tiles count twice
            if (b < TRI) { A = Xh; B = Xh; nA = nx; nB = nx;
                           coef = w / ((double)NROWS * (double)(NROWS - 1)); }
            else         { A = Yh; B = Yh; nA = ny; nB = ny;
                           coef = w / ((double)MROWS * (double)(MROWS - 1)); }
        } else {
            int u = b - 2 * TRI;
            tr = u / NT; tc = u % NT;
            A = Xh; B = Yh; nA = nx; nB = ny;
            coef = -2.0 / ((double)NROWS * (double)MROWS);
        }

        // staging setup: 16 glds instrs (2 tiles x 8 row-groups of 16 rows);
        // wave w issues instrs w*4..w*4+3; per instr 64 lanes x 16 B.
        const f16_t* Abase = A + (size_t)tr * BM * DDIM;
        const f16_t* Bbase = B + (size_t)tc * BM * DDIM;
        const f16_t* gsrc[4];
        int ldsoff[4];
        #pragma unroll
        for (int i = 0; i < 4; i++) {
            int idx = wave * 4 + i;      // 0..15
            int tile = idx >> 3;         // 0=A, 1=B
            int rg   = idx & 7;          // row-group
            const f16_t* base = tile ? Bbase : Abase;
            gsrc[i] = base + (size_t)(rg * 16 + lrow) * DDIM + lcol;
            ldsoff[i] = tile * TILE + (rg * 16 + lrow) * BK + lcol;
        }

        // epilogue norms hoisted off the critical tail
        float na[16], nb[4];
        #pragma unroll
        for (int i = 0; i < 4; i++) {
            #pragma unroll
            for (int r = 0; r < 4; r++)
                na[i * 4 + r] = nA[tr * BM + wm * 64 + i * 16 + quad * 4 + r];
            nb[i] = nB[tc * BM + wn * 64 + i * 16 + m];
        }

        floatx4 acc_r[4][4];
        #pragma unroll
        for (int i = 0; i < 4; i++)
            #pragma unroll
            for (int j = 0; j < 4; j++)
                acc_r[i][j] = (floatx4){0.f, 0.f, 0.f, 0.f};

        for (int k0 = 0; k0 < DDIM; k0 += BK) {
            __syncthreads();             // prev compute (or prev tile) done
            #pragma unroll
            for (int i = 0; i < 4; i++) {
                __builtin_amdgcn_global_load_lds(
                    (const __attribute__((address_space(1))) void*)(gsrc[i] + k0),
                    (__attribute__((address_space(3))) void*)(lds + ldsoff[i]),
                    16, 0, 0);
            }
            __syncthreads();             // drains vmcnt before barrier

            f16x8 ah[4], bh[4];
            #pragma unroll
            for (int s = 0; s < 4; s++) {
                int arow = wm * 64 + s * 16 + m;
                int brow = wn * 64 + s * 16 + m;
                ah[s] = *(const f16x8*)&lds[arow * BK + quad * 8];
                bh[s] = *(const f16x8*)&lds[TILE + brow * BK + quad * 8];
            }
            #pragma unroll
            for (int i = 0; i < 4; i++)
                #pragma unroll
                for (int j = 0; j < 4; j++)
                    acc_r[i][j] = __builtin_amdgcn_mfma_f32_16x16x32_f16(
                        ah[i], bh[j], acc_r[i][j], 0, 0, 0);
        }

        // epilogue: C/D layout col=lane&15 (B-row), row=quad*4+reg (A-row)
        const float inv_s2 = 1.0f / 2025.0f;
        float lsum = 0.f;
        #pragma unroll
        for (int i = 0; i < 4; i++)
            #pragma unroll
            for (int j = 0; j < 4; j++)
                #pragma unroll
                for (int r = 0; r < 4; r++) {
                    float arg = (2.f * acc_r[i][j][r] - na[i * 4 + r] - nb[j]) * inv_s2;
                    lsum += __expf(arg);
                }

        double d = (double)lsum;
        #pragma unroll
        for (int off = 32; off > 0; off >>= 1) d += __shfl_down(d, off);
        if (lane == 0) wred[wave] = d;
        __syncthreads();
        if (t == 0)
            mysum += (wred[0] + wred[1] + wred[2] + wred[3]) * coef;
        // next tile's first __syncthreads orders wred reuse
    }

    // ---------------- finalize ------------------------------------------
    if (t == 0) {
        atomicAdd(acc, mysum);           // device-scope atomic, coherent
        // RELEASE: orders the acc-add before the arrival count (emits L2
        // writeback only — no invalidate, so no R4-style cache poison).
        unsigned prev = __hip_atomic_fetch_add(cnt1, 1u, __ATOMIC_RELEASE,
                                               __HIP_MEMORY_SCOPE_AGENT);
        if (prev == PBLK - 1) {
            double total = atomicAdd(acc, 0.0);    // coherent RMW read-back
            out[0] = (float)(total - 1.0 / (double)(NROWS - 1)
                                   - 1.0 / (double)(MROWS - 1));
        }
    }
}

extern "C" void kernel_launch(void* const* d_in, const int* in_sizes, int n_in,
                              void* d_out, int out_size, void* d_ws, size_t ws_size,
                              hipStream_t stream) {
    const float* X = (const float*)d_in[0];   // inputs  [4096,1024] fp32
    const float* Y = (const float*)d_in[1];   // samples [4096,1024] fp32
    float* out = (float*)d_out;

    // workspace: cnt0 | cnt1 | acc(double) | pad | nx | ny | Xh | Yh
    char* p = (char*)d_ws;
    unsigned* cnt0 = (unsigned*)p;
    unsigned* cnt1 = (unsigned*)(p + 4);
    double* acc = (double*)(p + 8);
    p += 256;
    float* nx = (float*)p;                    p += (size_t)NROWS * sizeof(float);
    float* ny = (float*)p;                    p += (size_t)MROWS * sizeof(float);
    f16_t* Xh = (f16_t*)p;                    p += (size_t)NROWS * DDIM * sizeof(f16_t);
    f16_t* Yh = (f16_t*)p;

    hipMemsetAsync(d_ws, 0, 16, stream);      // zero cnt0, cnt1, acc
    mmd_fused<<<PBLK, 256, 0, stream>>>(X, Y, Xh, Yh, nx, ny,
                                        cnt0, cnt1, acc, out);
}

// Round 13
// 164.064 us; speedup vs baseline: 1.5250x; 1.5250x over previous
//
#include <hip/hip_runtime.h>
#include <math.h>

// MMD loss, single-pass fp16 MFMA. N=M=4096, D=1024, sigma^2=2025.
// x -> xh = fp16(x) (RNE); norms computed FROM THE ROUNDED vectors so the
// kernel evaluates the exact MMD of the perturbed sets {xh},{yh}. Per-block
// fp64 partials + tiny reduce kernel. 3-kernel structure (R12 proved graph
// replay gaps ~0 and fusion hurts L2 locality + pays barrier invalidates).
// Round 13: XCD-aware tile swizzle. Dispatch round-robins blockIdx over the
// 8 XCDs, so consecutive-b tiles (sharing tr / A-rows) previously landed on
// DIFFERENT XCDs -> each 4 MB L2 refetched ~the whole 16 MB working set
// (FETCH 128 MB = 8x). Remap b = (blockIdx%8)*260 + blockIdx/8 so each XCD
// owns 260 consecutive tiles: A-rows stay hot in its own L2.
// K-loop untouched: R5's two-barrier BK=32 structure (proven best of 8
// variants: dbuf/BK64/swizzle/no-LDS/fat-tiles all neutral or worse).

typedef _Float16 f16_t;
typedef _Float16 f16x4 __attribute__((ext_vector_type(4)));
typedef _Float16 f16x8 __attribute__((ext_vector_type(8)));
typedef float floatx4 __attribute__((ext_vector_type(4)));

#define NROWS 4096
#define MROWS 4096
#define DDIM  1024
#define BM    128
#define BK    32                      // fp16 elements per K-step (64 B/row)
#define TILE  (BM * BK)               // 4096 f16 per tile (8 KB)
#define NT    (NROWS / BM)            // 32 tiles per dim
#define TRI   (NT * (NT + 1) / 2)     // 528 triangular tiles
#define NBLK  (2 * TRI + NT * NT)     // 2080 blocks = 8 XCDs x 260

// ---------------------------------------------------------------- convert
// Wave-per-row: 2048 blocks x 4 waves cover 8192 rows. At the HBM roofline
// (~80 MB of traffic in ~13 us).
__global__ __launch_bounds__(256) void convert_kernel(
    const float* __restrict__ X, const float* __restrict__ Y,
    f16_t* __restrict__ Xh, f16_t* __restrict__ Yh,
    float* __restrict__ nx, float* __restrict__ ny) {
    const int wid  = threadIdx.x >> 6;
    const int lane = threadIdx.x & 63;
    const int row  = blockIdx.x * 4 + wid;        // 0..8191
    const float* src;
    f16_t* dst;
    float* nrm;
    int r;
    if (row < NROWS) {
        r = row;         src = X + (size_t)r * DDIM;
        dst = Xh + (size_t)r * DDIM;  nrm = nx;
    } else {
        r = row - NROWS; src = Y + (size_t)r * DDIM;
        dst = Yh + (size_t)r * DDIM;  nrm = ny;
    }
    const float4* s4 = (const float4*)src;        // 256 float4 per row
    f16x4* d4 = (f16x4*)dst;
    float s = 0.f;
    #pragma unroll
    for (int c = 0; c < 4; c++) {
        float4 v = s4[c * 64 + lane];
        f16x4 h;
        h[0] = (f16_t)v.x; h[1] = (f16_t)v.y;
        h[2] = (f16_t)v.z; h[3] = (f16_t)v.w;
        d4[c * 64 + lane] = h;
        float h0 = (float)h[0], h1 = (float)h[1];
        float h2 = (float)h[2], h3 = (float)h[3];
        s += h0 * h0 + h1 * h1 + h2 * h2 + h3 * h3;
    }
    #pragma unroll
    for (int off = 32; off > 0; off >>= 1) s += __shfl_down(s, off);
    if (lane == 0) nrm[r] = s;
}

// ---------------------------------------------------------------- main GEMM
__global__ __launch_bounds__(256) void mmd_mfma(
    const f16_t* __restrict__ Xh, const f16_t* __restrict__ Yh,
    const float* __restrict__ nx, const float* __restrict__ ny,
    double* __restrict__ partials) {
    // A-tile | B-tile, each BM x BK fp16 = 8 KB (16 KB total). Row-major,
    // row stride BK (64 B), contiguous (required by global_load_lds
    // wave-uniform-base + lane*16 semantics).
    __shared__ __align__(16) f16_t lds[2 * TILE];
    __shared__ double wred[4];

    // XCD swizzle: blockIdx%8 ~ XCD id (round-robin dispatch); give each
    // XCD a run of 260 consecutive logical tiles for A-row L2 residency.
    const int b = (blockIdx.x & 7) * (NBLK / 8) + (blockIdx.x >> 3);

    const f16_t *A, *B;
    const float *nA, *nB;
    int tr, tc;
    double coef;
    if (b < 2 * TRI) {
        int u = (b < TRI) ? b : b - TRI;
        int r = 0;
        while (u >= NT - r) { u -= NT - r; r++; }
        tr = r; tc = r + u;
        double w = (tr == tc) ? 1.0 : 2.0;   // off-diagonal tiles count twice
        if (b < TRI) { A = Xh; B = Xh; nA = nx; nB = nx;
                       coef = w / ((double)NROWS * (double)(NROWS - 1)); }
        else         { A = Yh; B = Yh; nA = ny; nB = ny;
                       coef = w / ((double)MROWS * (double)(MROWS - 1)); }
    } else {
        int u = b - 2 * TRI;
        tr = u / NT; tc = u % NT;
        A = Xh; B = Yh; nA = nx; nB = ny;
        coef = -2.0 / ((double)NROWS * (double)MROWS);
    }

    const int t    = threadIdx.x;
    const int wave = t >> 6;            // 0..3; waves 2x2: wm=wave>>1, wn=wave&1
    const int lane = t & 63;
    const int wm   = wave >> 1;
    const int wn   = wave & 1;

    // staging: 16 glds instrs (2 tiles x 8 row-groups of 16 rows); wave w
    // issues instrs w*4 .. w*4+3. Per instr: 64 lanes x 16 B = 16 rows.
    const f16_t* Abase = A + (size_t)tr * BM * DDIM;
    const f16_t* Bbase = B + (size_t)tc * BM * DDIM;
    const int lrow = lane >> 2;         // 0..15 within row-group
    const int lcol = (lane & 3) * 8;    // f16 elems; *2B = 16 B chunks
    const f16_t* gsrc[4];
    int ldsoff[4];
    #pragma unroll
    for (int i = 0; i < 4; i++) {
        int idx = wave * 4 + i;         // 0..15
        int tile = idx >> 3;            // 0=A, 1=B
        int rg   = idx & 7;             // row-group
        const f16_t* base = tile ? Bbase : Abase;
        gsrc[i] = base + (size_t)(rg * 16 + lrow) * DDIM + lcol;
        ldsoff[i] = tile * TILE + (rg * 16 + lrow) * BK + lcol;
    }

    const int m    = lane & 15;         // row within 16x16 subtile
    const int quad = lane >> 4;         // k-chunk: k = quad*8 + j

    // hoist epilogue norm loads off the critical tail
    float na[16], nb[4];
    #pragma unroll
    for (int i = 0; i < 4; i++) {
        #pragma unroll
        for (int r = 0; r < 4; r++)
            na[i * 4 + r] = nA[tr * BM + wm * 64 + i * 16 + quad * 4 + r];
        nb[i] = nB[tc * BM + wn * 64 + i * 16 + m];
    }

    floatx4 acc_r[4][4];
    #pragma unroll
    for (int i = 0; i < 4; i++)
        #pragma unroll
        for (int j = 0; j < 4; j++) acc_r[i][j] = (floatx4){0.f, 0.f, 0.f, 0.f};

    for (int k0 = 0; k0 < DDIM; k0 += BK) {
        __syncthreads();                 // previous compute done before overwrite
        #pragma unroll
        for (int i = 0; i < 4; i++) {
            __builtin_amdgcn_global_load_lds(
                (const __attribute__((address_space(1))) void*)(gsrc[i] + k0),
                (__attribute__((address_space(3))) void*)(lds + ldsoff[i]),
                16, 0, 0);
        }
        __syncthreads();                 // drains vmcnt before barrier

        f16x8 ah[4], bh[4];
        #pragma unroll
        for (int s = 0; s < 4; s++) {
            int arow = wm * 64 + s * 16 + m;
            int brow = wn * 64 + s * 16 + m;
            ah[s] = *(const f16x8*)&lds[arow * BK + quad * 8];
            bh[s] = *(const f16x8*)&lds[TILE + brow * BK + quad * 8];
        }
        #pragma unroll
        for (int i = 0; i < 4; i++)
            #pragma unroll
            for (int j = 0; j < 4; j++)
                acc_r[i][j] = __builtin_amdgcn_mfma_f32_16x16x32_f16(ah[i], bh[j], acc_r[i][j], 0, 0, 0);
    }

    // epilogue: C/D layout col=lane&15 (B-row), row=quad*4+reg (A-row)
    const float inv_s2 = 1.0f / 2025.0f;
    float lsum = 0.f;
    #pragma unroll
    for (int i = 0; i < 4; i++)
        #pragma unroll
        for (int j = 0; j < 4; j++)
            #pragma unroll
            for (int r = 0; r < 4; r++) {
                float arg = (2.f * acc_r[i][j][r] - na[i * 4 + r] - nb[j]) * inv_s2;
                lsum += __expf(arg);
            }

    // in-wave fp64 reduce (no barriers), then 4-wave LDS combine; plain store
    double d = (double)lsum;
    #pragma unroll
    for (int off = 32; off > 0; off >>= 1) d += __shfl_down(d, off);
    if (lane == 0) wred[wave] = d;
    __syncthreads();
    if (t == 0)
        partials[b] = (wred[0] + wred[1] + wred[2] + wred[3]) * coef;
}

__global__ __launch_bounds__(256) void final_reduce(const double* __restrict__ partials,
                                                    float* __restrict__ out) {
    __shared__ double red[256];
    int t = threadIdx.x;
    double s = 0.0;
    for (int i = t; i < NBLK; i += 256) s += partials[i];
    red[t] = s;
    __syncthreads();
    for (int off = 128; off > 0; off >>= 1) {
        if (t < off) red[t] += red[t + off];
        __syncthreads();
    }
    if (t == 0) {
        // analytic diagonal subtraction: 1/(n-1) + 1/(m-1)
        double mmd = red[0] - 1.0 / (double)(NROWS - 1) - 1.0 / (double)(MROWS - 1);
        out[0] = (float)mmd;
    }
}

extern "C" void kernel_launch(void* const* d_in, const int* in_sizes, int n_in,
                              void* d_out, int out_size, void* d_ws, size_t ws_size,
                              hipStream_t stream) {
    const float* X = (const float*)d_in[0];   // inputs  [4096,1024] fp32
    const float* Y = (const float*)d_in[1];   // samples [4096,1024] fp32
    float* out = (float*)d_out;

    // workspace: partials | nx | ny | Xh | Yh  (~16.7 MB)
    char* p = (char*)d_ws;
    double* partials = (double*)p;            p += ((size_t)NBLK * sizeof(double) + 255) & ~255ULL;
    float* nx = (float*)p;                    p += (size_t)NROWS * sizeof(float);
    float* ny = (float*)p;                    p += (size_t)MROWS * sizeof(float);
    f16_t* Xh = (f16_t*)p;                    p += (size_t)NROWS * DDIM * sizeof(f16_t);
    f16_t* Yh = (f16_t*)p;

    convert_kernel<<<(NROWS + MROWS) / 4, 256, 0, stream>>>(X, Y, Xh, Yh, nx, ny);
    mmd_mfma<<<NBLK, 256, 0, stream>>>(Xh, Yh, nx, ny, partials);
    final_reduce<<<1, 256, 0, stream>>>(partials, out);
}